// Round 4
// baseline (1276.958 us; speedup 1.0000x reference)
//
#include <hip/hip_runtime.h>
#include <cstdint>

// Problem constants: B=2, S=2048, HID=2048, H=16, D=128, K=4
#define BB 2
#define SS 2048
#define HID_ 2048
#define HH 16
#define DD 128
#define HD 2048
#define MM 4096
#define CC 64        // chunk length
#define NCH 32       // chunks per sequence
#define NU 1024      // units = 32 (b*h) * 32 chunks

typedef unsigned short u16;
typedef __bf16 bf16x8 __attribute__((ext_vector_type(8)));
typedef float f32x4 __attribute__((ext_vector_type(4)));
typedef unsigned short u16x8 __attribute__((ext_vector_type(8)));

__device__ __forceinline__ u16 f2bf(float f) {
  unsigned u = __float_as_uint(f);
  u += 0x7FFFu + ((u >> 16) & 1u);   // RNE
  return (u16)(u >> 16);
}
__device__ __forceinline__ float blo(unsigned u) { return __uint_as_float(u << 16); }
__device__ __forceinline__ float bhi(unsigned u) { return __uint_as_float(u & 0xffff0000u); }
__device__ __forceinline__ float sigmoidf_(float x) { return 1.0f / (1.0f + __expf(-x)); }

__device__ __forceinline__ void gll16(const void* g, void* l) {
  __builtin_amdgcn_global_load_lds((const __attribute__((address_space(1))) void*)g,
                                   (__attribute__((address_space(3))) void*)l, 16, 0, 0);
}

typedef union { unsigned q[4]; bf16x8 b; } fragu;

// build bf16x8 fragment  k[off..off+7] * exp(g - a)  (elementwise)
__device__ __forceinline__ bf16x8 decay_row8(const u16* kr, const float* gr, const float* ar, int off) {
  uint4 k8 = *(const uint4*)(kr + off);
  f32x4 g0 = *(const f32x4*)(gr + off);
  f32x4 g1 = *(const f32x4*)(gr + off + 4);
  f32x4 a0 = *(const f32x4*)(ar + off);
  f32x4 a1 = *(const f32x4*)(ar + off + 4);
  fragu r;
  r.q[0] = (unsigned)f2bf(blo(k8.x) * __expf(g0[0] - a0[0])) |
           ((unsigned)f2bf(bhi(k8.x) * __expf(g0[1] - a0[1])) << 16);
  r.q[1] = (unsigned)f2bf(blo(k8.y) * __expf(g0[2] - a0[2])) |
           ((unsigned)f2bf(bhi(k8.y) * __expf(g0[3] - a0[3])) << 16);
  r.q[2] = (unsigned)f2bf(blo(k8.z) * __expf(g1[0] - a1[0])) |
           ((unsigned)f2bf(bhi(k8.z) * __expf(g1[1] - a1[1])) << 16);
  r.q[3] = (unsigned)f2bf(blo(k8.w) * __expf(g1[2] - a1[2])) |
           ((unsigned)f2bf(bhi(k8.w) * __expf(g1[3] - a1[3])) << 16);
  return r.b;
}

// ---------------- elementwise f32 -> bf16 ----------------
__global__ void cvt_bf16_kernel(const float* __restrict__ in, u16* __restrict__ out, int n) {
  int i = blockIdx.x * blockDim.x + threadIdx.x;
  if (i < n) out[i] = f2bf(in[i]);
}

// ---------------- transpose + convert: in[K][N] f32 -> out[N][K] bf16 ----------------
__global__ __launch_bounds__(256) void transpose_bf16_kernel(
    const float* __restrict__ in, u16* __restrict__ out, int K, int N) {
  __shared__ float tile[32][33];
  int n0 = blockIdx.x * 32, k0 = blockIdx.y * 32;
  int tx = threadIdx.x, ty = threadIdx.y;
#pragma unroll
  for (int i = 0; i < 32; i += 8)
    tile[ty + i][tx] = in[(size_t)(k0 + ty + i) * N + (n0 + tx)];
  __syncthreads();
#pragma unroll
  for (int i = 0; i < 32; i += 8)
    out[(size_t)(n0 + ty + i) * K + (k0 + tx)] = f2bf(tile[tx][ty + i]);
}

// ---------------- bf16 MFMA GEMM: C[M][N] f32 = A[M][K] @ Bt[N][K]^T ----------------
__global__ __launch_bounds__(256) void gemm_bf16_kernel(
    const u16* __restrict__ A, const u16* __restrict__ Bt, float* __restrict__ C,
    int M, int N, int K) {
  __shared__ u16 As[128 * 32];
  __shared__ u16 Bs[128 * 32];
  const int tid = threadIdx.x;
  const int tileN = blockIdx.x * 128, tileM = blockIdx.y * 128;
  const int lane = tid & 63, wv = tid >> 6;
  const int wm = (wv & 1) * 64, wn = (wv >> 1) * 64;
  const int frm = lane & 15, fk = (lane >> 4) * 8;
  const int srow0 = 32 * wv + (lane >> 2);
  const int scol8 = (lane & 3) * 8;
  const u16* Ab0 = A + (size_t)(tileM + srow0) * K + scol8;
  const u16* Ab1 = A + (size_t)(tileM + srow0 + 16) * K + scol8;
  const u16* Bb0 = Bt + (size_t)(tileN + srow0) * K + scol8;
  const u16* Bb1 = Bt + (size_t)(tileN + srow0 + 16) * K + scol8;
  u16* AsL0 = &As[1024 * wv];
  u16* AsL1 = &As[1024 * wv + 512];
  u16* BsL0 = &Bs[1024 * wv];
  u16* BsL1 = &Bs[1024 * wv + 512];
  f32x4 acc[4][4];
#pragma unroll
  for (int i = 0; i < 4; ++i)
#pragma unroll
    for (int j = 0; j < 4; ++j) acc[i][j] = (f32x4)0.0f;
  for (int k0 = 0; k0 < K; k0 += 32) {
    gll16(Ab0 + k0, AsL0);
    gll16(Ab1 + k0, AsL1);
    gll16(Bb0 + k0, BsL0);
    gll16(Bb1 + k0, BsL1);
    __syncthreads();
    bf16x8 af[4], bfr[4];
#pragma unroll
    for (int t = 0; t < 4; ++t)
      af[t] = *(const bf16x8*)(&As[(wm + t * 16 + frm) * 32 + fk]);
#pragma unroll
    for (int t = 0; t < 4; ++t)
      bfr[t] = *(const bf16x8*)(&Bs[(wn + t * 16 + frm) * 32 + fk]);
#pragma unroll
    for (int mt = 0; mt < 4; ++mt)
#pragma unroll
      for (int nt = 0; nt < 4; ++nt)
        acc[mt][nt] = __builtin_amdgcn_mfma_f32_16x16x32_bf16(af[mt], bfr[nt], acc[mt][nt], 0, 0, 0);
    __syncthreads();
  }
  const int crow = (lane >> 4) * 4, ccol = lane & 15;
#pragma unroll
  for (int mt = 0; mt < 4; ++mt)
#pragma unroll
    for (int nt = 0; nt < 4; ++nt) {
      float* cp = C + (size_t)(tileM + wm + mt * 16 + crow) * N + (tileN + wn + nt * 16 + ccol);
#pragma unroll
      for (int i = 0; i < 4; ++i) cp[(size_t)i * N] = acc[mt][nt][i];
    }
}

// ---------------- l2norm over D=128, in-place ----------------
__global__ __launch_bounds__(256) void l2norm_kernel(float* __restrict__ x) {
  int idx = blockIdx.x * 4 + (threadIdx.x >> 6);
  int lane = threadIdx.x & 63;
  float* p = x + (size_t)idx * DD;
  float2 v = *(float2*)(p + lane * 2);
  float ss = v.x * v.x + v.y * v.y;
#pragma unroll
  for (int o = 32; o > 0; o >>= 1) ss += __shfl_xor(ss, o);
  float r = rsqrtf(ss + 1e-6f);
  v.x *= r; v.y *= r;
  *(float2*)(p + lane * 2) = v;
}

// ---------------- causal depthwise conv (K=4) + SiLU ----------------
__global__ void conv_silu_kernel(const float* __restrict__ x, const float* __restrict__ w,
                                 float* __restrict__ y, int n) {
  int id = blockIdx.x * blockDim.x + threadIdx.x;
  if (id >= n) return;
  int c = id & (HD - 1);
  int s = (id >> 11) & (SS - 1);
  float acc = 0.f;
#pragma unroll
  for (int t = 0; t < 4; ++t) {
    int sp = s - 3 + t;
    if (sp >= 0) acc += w[t * HD + c] * x[id + (t - 3) * HD];
  }
  y[id] = acc * sigmoidf_(acc);
}

// ---------------- beta = sigmoid(hidden @ Wb) ----------------
__global__ __launch_bounds__(256) void beta_kernel(const float* __restrict__ hid,
                                                   const float* __restrict__ Wb,
                                                   float* __restrict__ beta) {
  int row = blockIdx.x;
  int tid = threadIdx.x;
  int h = tid & 15, chunk = tid >> 4;
  const float* hp = hid + (size_t)row * HID_;
  float acc = 0.f;
  int d0 = chunk * 128;
  for (int i = 0; i < 128; ++i) acc += hp[d0 + i] * Wb[(size_t)(d0 + i) * 16 + h];
  __shared__ float red[256];
  red[tid] = acc;
  __syncthreads();
  if (tid < 16) {
    float s = 0.f;
#pragma unroll
    for (int j = 0; j < 16; ++j) s += red[j * 16 + tid];
    beta[(size_t)row * 16 + tid] = 1.f / (1.f + __expf(-s));
  }
}

// ---------------- g = -exp(A_log[h]) * softplus(glin + dt_bias), in-place ----------------
__global__ void kda_g_kernel(float* __restrict__ glin, const float* __restrict__ A_log,
                             const float* __restrict__ dt_bias, int n) {
  int id = blockIdx.x * blockDim.x + threadIdx.x;
  if (id >= n) return;
  int c = id & (HD - 1);
  int h = c >> 7;
  float x = glin[id] + dt_bias[c];
  float sp = (x > 20.f) ? x : log1pf(__expf(x));
  glin[id] = -__expf(A_log[h]) * sp;
}

// ---------------- chunk_prepA: anchored-MFMA A/G + packed tensors ----------------
// Outputs:
//   G  [unit][t*64+j] bf16 (Gt)        M = beta*A [unit][t*64+j] bf16 (Mg, lower valid)
//   Q~ [unit][t*128+k] bf16 (Qp)       X~ [unit][k*64+t] bf16 (Xp)
//   W  = beta*k*e^gc [unit][t*128+k] bf16 (Wg)     dlast f32 [unit][128] (dl)
__global__ __launch_bounds__(256) void chunk_prepA(
    const float* __restrict__ q, const float* __restrict__ k,
    const float* __restrict__ g, const float* __restrict__ beta,
    u16* __restrict__ Gt, u16* __restrict__ Mg, u16* __restrict__ Wg,
    float* __restrict__ dl, u16* __restrict__ Qp, u16* __restrict__ Xp) {
  __shared__ float gcl[CC * 132];   // 33792 B; col 128 holds beta[t]
  __shared__ u16 kb[CC * 136];      // 17408 B
  __shared__ u16 qd[16 * 128];      // 4096 B  (current I block of q*scale, bf16)
  __shared__ u16 Gli[16 * 64];      // 2048 B
  __shared__ u16 MlI[16 * 64];      // 2048 B
  const int tid = threadIdx.x;
  const int chunk = blockIdx.x & 31, bh = blockIdx.x >> 5;
  const int h = bh & 15, b = bh >> 4;
  const size_t unit = (size_t)bh * NCH + chunk;
  const size_t base = ((size_t)b * SS + (size_t)chunk * CC) * HD + (size_t)h * DD;
  const float scale = 0.08838834764831845f;
  const int w = tid >> 6, lane = tid & 63;
  const int frm = lane & 15, fk = (lane >> 4) * 8;
  const int crow = (lane >> 4) * 4, ccol = lane & 15;

  // phase 1: stage k (bf16), beta, cumsum g
  {
    int t = tid >> 2, seg = tid & 3;
    const float* kr = k + base + (size_t)t * HD + seg * 32;
    float kv[32];
#pragma unroll
    for (int i = 0; i < 8; ++i) *(f32x4*)&kv[4 * i] = *(const f32x4*)(kr + 4 * i);
    unsigned pu[16];
#pragma unroll
    for (int i = 0; i < 16; ++i)
      pu[i] = (unsigned)f2bf(kv[2 * i]) | ((unsigned)f2bf(kv[2 * i + 1]) << 16);
    uint4* dst = (uint4*)&kb[t * 136 + seg * 32];
#pragma unroll
    for (int i = 0; i < 4; ++i) dst[i] = make_uint4(pu[4 * i], pu[4 * i + 1], pu[4 * i + 2], pu[4 * i + 3]);
  }
  if (tid < CC) gcl[tid * 132 + 128] = beta[((size_t)b * SS + (size_t)chunk * CC + tid) * HH + h];
  if (tid < DD) {
    float acc = 0.f;
    for (int t = 0; t < CC; ++t) {
      acc += g[base + (size_t)t * HD + tid];
      gcl[t * 132 + tid] = acc;
    }
  }
  __syncthreads();

  // phase 2: I-blocks
#pragma unroll 1
  for (int I = 0; I < 4; ++I) {
    const int aI = 16 * I;
    // zero Gli + stage qd rows of block I
    for (int e = tid; e < 512; e += 256) ((unsigned*)Gli)[e] = 0;
    {
      int tl = tid >> 4, c0 = (tid & 15) * 8;
      const float* qr = q + base + (size_t)(aI + tl) * HD + c0;
      f32x4 q0 = *(const f32x4*)qr;
      f32x4 q1 = *(const f32x4*)(qr + 4);
      uint4 o;
      o.x = (unsigned)f2bf(q0[0] * scale) | ((unsigned)f2bf(q0[1] * scale) << 16);
      o.y = (unsigned)f2bf(q0[2] * scale) | ((unsigned)f2bf(q0[3] * scale) << 16);
      o.z = (unsigned)f2bf(q1[0] * scale) | ((unsigned)f2bf(q1[1] * scale) << 16);
      o.w = (unsigned)f2bf(q1[2] * scale) | ((unsigned)f2bf(q1[3] * scale) << 16);
      *(uint4*)&qd[tl * 128 + c0] = o;
    }
    __syncthreads();
    // diagonal 16x16 triangle, pairwise-safe exps
    {
      const int tl = tid >> 4, jl = tid & 15;
      const int rt = aI + tl, rj = aI + jl;
      float accA = 0.f, accG = 0.f;
#pragma unroll
      for (int c0 = 0; c0 < 128; c0 += 8) {
        f32x4 gt0 = *(const f32x4*)&gcl[rt * 132 + c0];
        f32x4 gt1 = *(const f32x4*)&gcl[rt * 132 + c0 + 4];
        f32x4 gj0 = *(const f32x4*)&gcl[rj * 132 + c0];
        f32x4 gj1 = *(const f32x4*)&gcl[rj * 132 + c0 + 4];
        uint4 kt4 = *(const uint4*)&kb[rt * 136 + c0];
        uint4 kj4 = *(const uint4*)&kb[rj * 136 + c0];
        uint4 qt4 = *(const uint4*)&qd[tl * 128 + c0];
        float e, p;
        e = __expf(gt0[0] - gj0[0]); p = blo(kj4.x) * e; accA += blo(kt4.x) * p; accG += blo(qt4.x) * p;
        e = __expf(gt0[1] - gj0[1]); p = bhi(kj4.x) * e; accA += bhi(kt4.x) * p; accG += bhi(qt4.x) * p;
        e = __expf(gt0[2] - gj0[2]); p = blo(kj4.y) * e; accA += blo(kt4.y) * p; accG += blo(qt4.y) * p;
        e = __expf(gt0[3] - gj0[3]); p = bhi(kj4.y) * e; accA += bhi(kt4.y) * p; accG += bhi(qt4.y) * p;
        e = __expf(gt1[0] - gj1[0]); p = blo(kj4.z) * e; accA += blo(kt4.z) * p; accG += blo(qt4.z) * p;
        e = __expf(gt1[1] - gj1[1]); p = bhi(kj4.z) * e; accA += bhi(kt4.z) * p; accG += bhi(qt4.z) * p;
        e = __expf(gt1[2] - gj1[2]); p = blo(kj4.w) * e; accA += blo(kt4.w) * p; accG += blo(qt4.w) * p;
        e = __expf(gt1[3] - gj1[3]); p = bhi(kj4.w) * e; accA += bhi(kt4.w) * p; accG += bhi(qt4.w) * p;
      }
      if (jl <= tl) Gli[tl * 64 + aI + jl] = f2bf(accG);
      if (jl < tl) MlI[tl * 64 + aI + jl] = f2bf(gcl[rt * 132 + 128] * accA);
    }
    // off-diagonal tiles via MFMA (waves 0: A, 1: G), fragments built on the fly
    if (w < 2) {
      const int rt = aI + frm;
      bf16x8 af[4];
#pragma unroll
      for (int kb2 = 0; kb2 < 4; ++kb2) {
        int off = kb2 * 32 + fk;
        if (w == 0)
          af[kb2] = decay_row8(&kb[rt * 136], &gcl[rt * 132], &gcl[aI * 132], off);
        else
          af[kb2] = decay_row8(&qd[frm * 128], &gcl[rt * 132], &gcl[aI * 132], off);
      }
      for (int J = 0; J < I; ++J) {
        const int rj = 16 * J + frm;
        f32x4 acc = (f32x4)0.f;
#pragma unroll
        for (int kb2 = 0; kb2 < 4; ++kb2) {
          int off = kb2 * 32 + fk;
          bf16x8 bf = decay_row8(&kb[rj * 136], &gcl[aI * 132], &gcl[rj * 132], off);
          acc = __builtin_amdgcn_mfma_f32_16x16x32_bf16(af[kb2], bf, acc, 0, 0, 0);
        }
        if (w == 0) {
#pragma unroll
          for (int i = 0; i < 4; ++i) {
            float bt = gcl[(aI + crow + i) * 132 + 128];
            MlI[(crow + i) * 64 + 16 * J + ccol] = f2bf(bt * acc[i]);
          }
        } else {
#pragma unroll
          for (int i = 0; i < 4; ++i)
            Gli[(crow + i) * 64 + 16 * J + ccol] = f2bf(acc[i]);
        }
      }
    }
    __syncthreads();
    // flush G, M rows (coalesced) + Q~ rows of this block
    if (tid < 128) {
      int t = tid >> 3, j0 = (tid & 7) * 8;
      *(uint4*)(Gt + unit * 4096 + (size_t)(aI + t) * 64 + j0) = *(const uint4*)&Gli[t * 64 + j0];
    } else {
      int t2 = (tid - 128) >> 3, j0 = ((tid - 128) & 7) * 8;
      *(uint4*)(Mg + unit * 4096 + (size_t)(aI + t2) * 64 + j0) = *(const uint4*)&MlI[t2 * 64 + j0];
    }
    {
      int tl = tid >> 4, c0 = (tid & 15) * 8;
      const int rt = aI + tl;
      uint4 q8 = *(const uint4*)&qd[tl * 128 + c0];
      f32x4 g0 = *(const f32x4*)&gcl[rt * 132 + c0];
      f32x4 g1 = *(const f32x4*)&gcl[rt * 132 + c0 + 4];
      uint4 o;
      o.x = (unsigned)f2bf(blo(q8.x) * __expf(g0[0])) | ((unsigned)f2bf(bhi(q8.x) * __expf(g0[1])) << 16);
      o.y = (unsigned)f2bf(blo(q8.y) * __expf(g0[2])) | ((unsigned)f2bf(bhi(q8.y) * __expf(g0[3])) << 16);
      o.z = (unsigned)f2bf(blo(q8.z) * __expf(g1[0])) | ((unsigned)f2bf(bhi(q8.z) * __expf(g1[1])) << 16);
      o.w = (unsigned)f2bf(blo(q8.w) * __expf(g1[2])) | ((unsigned)f2bf(bhi(q8.w) * __expf(g1[3])) << 16);
      *(uint4*)(Qp + unit * 8192 + (size_t)rt * 128 + c0) = o;
    }
    __syncthreads();
  }

  // phase 3: X~ transposed [k][t]
#pragma unroll
  for (int r = 0; r < 4; ++r) {
    int c = (tid >> 3) + r * 32;
    int t8 = (tid & 7) * 8;
    float gl = gcl[63 * 132 + c];
    unsigned pu[4];
#pragma unroll
    for (int i = 0; i < 4; ++i) {
      int t0 = t8 + 2 * i;
      float x0 = blo((unsigned)kb[t0 * 136 + c]) * __expf(gl - gcl[t0 * 132 + c]);
      float x1 = blo((unsigned)kb[(t0 + 1) * 136 + c]) * __expf(gl - gcl[(t0 + 1) * 132 + c]);
      pu[i] = (unsigned)f2bf(x0) | ((unsigned)f2bf(x1) << 16);
    }
    *(uint4*)(Xp + unit * 8192 + (size_t)c * 64 + t8) = make_uint4(pu[0], pu[1], pu[2], pu[3]);
  }
  if (tid < DD) dl[unit * DD + tid] = __expf(gcl[63 * 132 + tid]);
  // phase 4: W = beta * k * e^gc  (solve RHS, bf16 dense)
  {
    int t = tid >> 2, c0 = (tid & 3) * 32;
    float bt = gcl[t * 132 + 128];
#pragma unroll
    for (int s4 = 0; s4 < 4; ++s4) {
      uint4 k8 = *(const uint4*)&kb[t * 136 + c0 + s4 * 8];
      f32x4 g0 = *(const f32x4*)&gcl[t * 132 + c0 + s4 * 8];
      f32x4 g1 = *(const f32x4*)&gcl[t * 132 + c0 + s4 * 8 + 4];
      uint4 o;
      o.x = (unsigned)f2bf(bt * blo(k8.x) * __expf(g0[0])) | ((unsigned)f2bf(bt * bhi(k8.x) * __expf(g0[1])) << 16);
      o.y = (unsigned)f2bf(bt * blo(k8.y) * __expf(g0[2])) | ((unsigned)f2bf(bt * bhi(k8.y) * __expf(g0[3])) << 16);
      o.z = (unsigned)f2bf(bt * blo(k8.z) * __expf(g1[0])) | ((unsigned)f2bf(bt * bhi(k8.z) * __expf(g1[1])) << 16);
      o.w = (unsigned)f2bf(bt * blo(k8.w) * __expf(g1[2])) | ((unsigned)f2bf(bt * bhi(k8.w) * __expf(g1[3])) << 16);
      *(uint4*)(Wg + unit * 8192 + (size_t)t * 128 + c0 + s4 * 8) = o;
    }
  }
}

// ---------------- solve_kernel: (I+M) X = [beta*V | W]; P, Uv out ----------------
__global__ __launch_bounds__(256) void solve_kernel(
    const u16* __restrict__ Mg, const u16* __restrict__ Wg,
    float* __restrict__ v, const float* __restrict__ beta, u16* __restrict__ P) {
  __shared__ u16 Ml[CC * CC];
  __shared__ float betal[CC];
  const int tid = threadIdx.x;
  const int chunk = blockIdx.x & 31, bh = blockIdx.x >> 5;
  const int h = bh & 15, b = bh >> 4;
  const size_t unit = (size_t)bh * NCH + chunk;
  const size_t base = ((size_t)b * SS + (size_t)chunk * CC) * HD + (size_t)h * DD;
  ((uint4*)Ml)[tid] = ((const uint4*)(Mg + unit * 4096))[tid];
  ((uint4*)Ml)[tid + 256] = ((const uint4*)(Mg + unit * 4096))[tid + 256];
  if (tid < CC) betal[tid] = beta[((size_t)b * SS + (size_t)chunk * CC + tid) * HH + h];
  __syncthreads();
  const int c = tid & 127;
  const bool isV = tid < 128;
  float X[CC];
#pragma unroll
  for (int t = 0; t < CC; ++t) {
    if (isV) X[t] = betal[t] * v[base + (size_t)t * HD + c];
    else X[t] = blo((unsigned)Wg[unit * 8192 + t * 128 + c]);
  }
#pragma unroll
  for (int i = 1; i < CC; ++i) {
    float acc = X[i];
#pragma unroll
    for (int jb = 0; jb * 8 < i; ++jb) {
      uint4 mm = *(const uint4*)&Ml[i * CC + jb * 8];
      const int j0 = jb * 8;
      if (j0 + 0 < i) acc -= blo(mm.x) * X[j0 + 0];
      if (j0 + 1 < i) acc -= bhi(mm.x) * X[j0 + 1];
      if (j0 + 2 < i) acc -= blo(mm.y) * X[j0 + 2];
      if (j0 + 3 < i) acc -= bhi(mm.y) * X[j0 + 3];
      if (j0 + 4 < i) acc -= blo(mm.z) * X[j0 + 4];
      if (j0 + 5 < i) acc -= bhi(mm.z) * X[j0 + 5];
      if (j0 + 6 < i) acc -= blo(mm.w) * X[j0 + 6];
      if (j0 + 7 < i) acc -= bhi(mm.w) * X[j0 + 7];
    }
    X[i] = acc;
  }
#pragma unroll
  for (int t = 0; t < CC; ++t) {
    if (isV) v[base + (size_t)t * HD + c] = X[t];
    else P[unit * 8192 + t * 128 + c] = f2bf(X[t]);
  }
}

// ---------------- state_pass: sequential S-chain; grid (8 vslices, 32 bh) ----------------
__global__ __launch_bounds__(256) void state_pass(
    const u16* __restrict__ P, const u16* __restrict__ Xp,
    const float* __restrict__ Uvg, const float* __restrict__ dl,
    u16* __restrict__ Sst) {
  __shared__ u16 Pb[64 * 136];    // [t][k] padded
  __shared__ u16 Xb[128 * 72];    // [k][t] padded
  __shared__ float S[128 * 20];   // [k][c] c<16, padded
  __shared__ float U[64 * 20];    // [t][c]
  __shared__ float dll[128];
  const int tid = threadIdx.x;
  const int vs = blockIdx.x, bh = blockIdx.y;
  const int h = bh & 15, b = bh >> 4;
  for (int i = tid; i < 128 * 20; i += 256) S[i] = 0.f;
  __syncthreads();
  for (int c = 0; c < NCH; ++c) {
    const size_t unit = (size_t)bh * NCH + c;
    const size_t base = ((size_t)b * SS + (size_t)c * CC) * HD + (size_t)h * DD + vs * 16;
#pragma unroll
    for (int r = 0; r < 4; ++r) {
      int e = r * 256 + tid;
      int t = e >> 4, kp = (e & 15) * 8;
      *(uint4*)&Pb[t * 136 + kp] = ((const uint4*)(P + unit * 8192))[e];
      int kk = e >> 3, tp = (e & 7) * 8;
      *(uint4*)&Xb[kk * 72 + tp] = ((const uint4*)(Xp + unit * 8192))[e];
    }
    {
      int t = tid >> 2, cg = tid & 3;
      *(f32x4*)&U[t * 20 + cg * 4] = *(const f32x4*)(Uvg + base + (size_t)t * HD + cg * 4);
    }
    if (tid < 128) dll[tid] = dl[unit * DD + tid];
    {
      int v2 = tid >> 4, kq = tid & 15;
      unsigned pu[4];
#pragma unroll
      for (int j = 0; j < 4; ++j) {
        float a = S[(kq * 8 + 2 * j) * 20 + v2];
        float bb = S[(kq * 8 + 2 * j + 1) * 20 + v2];
        pu[j] = (unsigned)f2bf(a) | ((unsigned)f2bf(bb) << 16);
      }
      *(uint4*)(Sst + unit * 16384 + (size_t)(vs * 16 + v2) * 128 + kq * 8) =
          make_uint4(pu[0], pu[1], pu[2], pu[3]);
    }
    __syncthreads();
    {
      const int t = tid >> 2, cg = tid & 3;
      f32x4 u = *(f32x4*)&U[t * 20 + cg * 4];
      f32x4 acc = (f32x4)0.f;
      for (int kk = 0; kk < 128; kk += 4) {
        uint2 pk = *(const uint2*)&Pb[t * 136 + kk];
        f32x4 s0 = *(const f32x4*)&S[(kk + 0) * 20 + cg * 4];
        f32x4 s1 = *(const f32x4*)&S[(kk + 1) * 20 + cg * 4];
        f32x4 s2 = *(const f32x4*)&S[(kk + 2) * 20 + cg * 4];
        f32x4 s3 = *(const f32x4*)&S[(kk + 3) * 20 + cg * 4];
        acc += blo(pk.x) * s0;
        acc += bhi(pk.x) * s1;
        acc += blo(pk.y) * s2;
        acc += bhi(pk.y) * s3;
      }
      u -= acc;
      *(f32x4*)&U[t * 20 + cg * 4] = u;
    }
    __syncthreads();
    {
      const int kk = tid >> 1, cg2 = tid & 1;
      f32x4 sa = *(f32x4*)&S[kk * 20 + cg2 * 8];
      f32x4 sb = *(f32x4*)&S[kk * 20 + cg2 * 8 + 4];
      float dk = dll[kk];
      sa *= dk; sb *= dk;
      for (int t4 = 0; t4 < 64; t4 += 4) {
        uint2 xv = *(const uint2*)&Xb[kk * 72 + t4];
        float x0 = blo(xv.x), x1 = bhi(xv.x), x2 = blo(xv.y), x3 = bhi(xv.y);
        f32x4 u0a = *(const f32x4*)&U[(t4 + 0) * 20 + cg2 * 8];
        f32x4 u0b = *(const f32x4*)&U[(t4 + 0) * 20 + cg2 * 8 + 4];
        f32x4 u1a = *(const f32x4*)&U[(t4 + 1) * 20 + cg2 * 8];
        f32x4 u1b = *(const f32x4*)&U[(t4 + 1) * 20 + cg2 * 8 + 4];
        f32x4 u2a = *(const f32x4*)&U[(t4 + 2) * 20 + cg2 * 8];
        f32x4 u2b = *(const f32x4*)&U[(t4 + 2) * 20 + cg2 * 8 + 4];
        f32x4 u3a = *(const f32x4*)&U[(t4 + 3) * 20 + cg2 * 8];
        f32x4 u3b = *(const f32x4*)&U[(t4 + 3) * 20 + cg2 * 8 + 4];
        sa += x0 * u0a; sb += x0 * u0b;
        sa += x1 * u1a; sb += x1 * u1b;
        sa += x2 * u2a; sb += x2 * u2b;
        sa += x3 * u3a; sb += x3 * u3b;
      }
      *(f32x4*)&S[kk * 20 + cg2 * 8] = sa;
      *(f32x4*)&S[kk * 20 + cg2 * 8 + 4] = sb;
    }
    __syncthreads();
  }
}

// ---------------- out_pass: o = Q~*S + G*(Uv - P*S), MFMA; grid 1024 ----------------
__global__ __launch_bounds__(256) void out_pass(
    const u16* __restrict__ P, const u16* __restrict__ Qp,
    const u16* __restrict__ G, const u16* __restrict__ Sst,
    const float* __restrict__ Uvg, float* __restrict__ attn) {
  __shared__ u16 Sb[128 * 136];   // [v][k]
  __shared__ u16 Pb[64 * 136];    // [t][k]
  __shared__ u16 Qb[64 * 136];    // [t][k]
  __shared__ u16 Gb[64 * 72];     // [t][j]
  __shared__ u16 Ub[128 * 72];    // U^T [v][t]
  const int tid = threadIdx.x;
  const int unit = blockIdx.x;
  const int bh = unit >> 5, c = unit & 31;
  const int h = bh & 15, b = bh >> 4;
  const size_t base = ((size_t)b * SS + (size_t)c * CC) * HD + (size_t)h * DD;
#pragma unroll
  for (int r = 0; r < 8; ++r) {
    int e = r * 256 + tid;
    int v = e >> 4, kp = (e & 15) * 8;
    *(uint4*)&Sb[v * 136 + kp] = ((const uint4*)(Sst + (size_t)unit * 16384))[e];
  }
#pragma unroll
  for (int r = 0; r < 4; ++r) {
    int e = r * 256 + tid;
    int t = e >> 4, kp = (e & 15) * 8;
    *(uint4*)&Pb[t * 136 + kp] = ((const uint4*)(P + (size_t)unit * 8192))[e];
    *(uint4*)&Qb[t * 136 + kp] = ((const uint4*)(Qp + (size_t)unit * 8192))[e];
  }
#pragma unroll
  for (int r = 0; r < 2; ++r) {
    int e = r * 256 + tid;
    int t = e >> 3, jp = (e & 7) * 8;
    *(uint4*)&Gb[t * 72 + jp] = ((const uint4*)(G + (size_t)unit * 4096))[e];
  }
  __syncthreads();
  const int w = tid >> 6, lane = tid & 63;
  const int frm = lane & 15, fk = (lane >> 4) * 8;
  const int crow = (lane >> 4) * 4, ccol = lane & 15;
  bf16x8 Pf[4], Qf[4], Gf[2];
#pragma unroll
  for (int kb2 = 0; kb2 < 4; ++kb2) {
    Pf[kb2] = *(const bf16x8*)&Pb[(w * 16 + frm) * 136 + kb2 * 32 + fk];
    Qf[kb2] = *(const bf16x8*)&Qb[(w * 16 + frm) * 136 + kb2 * 32 + fk];
  }
#pragma unroll
  for (int kb2 = 0; kb2 < 2; ++kb2)
    Gf[kb2] = *(const bf16x8*)&Gb[(w * 16 + frm) * 72 + kb2 * 32 + fk];
  f32x4 aps[8], ao[8];
#pragma unroll
  for (int nt = 0; nt < 8; ++nt) { aps[nt] = (f32x4)0.f; ao[nt] = (f32x4)0.f; }
#pragma unroll
  for (int nt = 0; nt < 8; ++nt)
#pragma unroll
    for (int kb2 = 0; kb2 < 4; ++kb2) {
      bf16x8 sf = *(const bf16x8*)&Sb[(nt * 16 + frm) * 136 + kb2 * 32 + fk];
      aps[nt] = __builtin_amdgcn_mfma_f32_16x16x32_bf16(Pf[kb2], sf, aps[nt], 0, 0, 0);
      ao[nt] = __builtin_amdgcn_mfma_f32_16x16x32_bf16(Qf[kb2], sf, ao[nt], 0, 0, 0);
    }
#pragma unroll
  for (int nt = 0; nt < 8; ++nt) {
    float un[4];
#pragma unroll
    for (int i = 0; i < 4; ++i) {
      float uv = Uvg[base + (size_t)(w * 16 + crow + i) * HD + nt * 16 + ccol];
      un[i] = uv - aps[nt][i];
    }
    uint2 pk = make_uint2((unsigned)f2bf(un[0]) | ((unsigned)f2bf(un[1]) << 16),
                          (unsigned)f2bf(un[2]) | ((unsigned)f2bf(un[3]) << 16));
    *(uint2*)&Ub[(nt * 16 + ccol) * 72 + w * 16 + crow] = pk;
  }
  __syncthreads();
#pragma unroll
  for (int nt = 0; nt < 8; ++nt)
#pragma unroll
    for (int kb2 = 0; kb2 < 2; ++kb2) {
      bf16x8 uf = *(const bf16x8*)&Ub[(nt * 16 + frm) * 72 + kb2 * 32 + fk];
      ao[nt] = __builtin_amdgcn_mfma_f32_16x16x32_bf16(Gf[kb2], uf, ao[nt], 0, 0, 0);
    }
#pragma unroll
  for (int nt = 0; nt < 8; ++nt)
#pragma unroll
    for (int i = 0; i < 4; ++i)
      attn[base + (size_t)(w * 16 + crow + i) * HD + nt * 16 + ccol] = ao[nt][i];
}

// ---------------- RMSNorm * rms_scale * sigmoid(gate) -> bf16 preout ----------------
__global__ __launch_bounds__(256) void gate_rms_kernel(
    const float* __restrict__ attn, const float* __restrict__ gate,
    const float* __restrict__ rms_scale, u16* __restrict__ preout) {
  int idx = blockIdx.x * 4 + (threadIdx.x >> 6);
  int lane = threadIdx.x & 63;
  const float* ap = attn + (size_t)idx * DD;
  const float* gp = gate + (size_t)idx * DD;
  float2 a = *(const float2*)(ap + lane * 2);
  float ss = a.x * a.x + a.y * a.y;
#pragma unroll
  for (int o = 32; o > 0; o >>= 1) ss += __shfl_xor(ss, o);
  float r = rsqrtf(ss * (1.0f / 128.0f) + 1e-5f);
  float2 gg = *(const float2*)(gp + lane * 2);
  int d = lane * 2;
  float o0 = a.x * r * rms_scale[d] * sigmoidf_(gg.x);
  float o1 = a.y * r * rms_scale[d + 1] * sigmoidf_(gg.y);
  preout[(size_t)idx * DD + d] = f2bf(o0);
  preout[(size_t)idx * DD + d + 1] = f2bf(o1);
}

extern "C" void kernel_launch(void* const* d_in, const int* in_sizes, int n_in,
                              void* d_out, int out_size, void* d_ws, size_t ws_size,
                              hipStream_t stream) {
  const float* hid = (const float*)d_in[0];
  const float* Wq = (const float*)d_in[1];
  const float* Wk = (const float*)d_in[2];
  const float* Wv = (const float*)d_in[3];
  const float* conv_q = (const float*)d_in[4];
  const float* conv_k = (const float*)d_in[5];
  const float* conv_v = (const float*)d_in[6];
  const float* Wb = (const float*)d_in[7];
  const float* Wfa = (const float*)d_in[8];
  const float* Wfb = (const float*)d_in[9];
  const float* Wga = (const float*)d_in[10];
  const float* Wgb = (const float*)d_in[11];
  const float* A_log = (const float*)d_in[12];
  const float* dt_bias = (const float*)d_in[13];
  const float* rms_scale = (const float*)d_in[14];
  const float* Wo = (const float*)d_in[15];
  float* out = (float*)d_out;
  (void)in_sizes; (void)n_in; (void)out_size; (void)ws_size;

  char* w = (char*)d_ws;
  size_t off = 0;
  auto alloc = [&](size_t bytes) -> void* {
    void* p = w + off;
    off += (bytes + 255) & ~(size_t)255;
    return p;
  };
  u16* hidb = (u16*)alloc((size_t)MM * HID_ * 2);   // -> P (dense), then preout
  u16* WqT  = (u16*)alloc((size_t)HD * HID_ * 2);   // -> G (dense)
  u16* WkT  = (u16*)alloc((size_t)HD * HID_ * 2);   // -> Qp (with WvT, contiguous)
  u16* WvT  = (u16*)alloc((size_t)HD * HID_ * 2);
  u16* WoT  = (u16*)alloc((size_t)HID_ * HD * 2);
  u16* WfaT = (u16*)alloc((size_t)DD * HID_ * 2);
  u16* WgaT = (u16*)alloc((size_t)DD * HID_ * 2);
  u16* WfbT = (u16*)alloc((size_t)HD * DD * 2);
  u16* WgbT = (u16*)alloc((size_t)HD * DD * 2);
  float* X1 = (float*)alloc((size_t)MM * HD * 4);   // kproj -> kc
  float* X2 = (float*)alloc((size_t)MM * HD * 4);   // vproj -> vc -> Uv (in place)
  float* X3 = (float*)alloc((size_t)MM * HD * 4);   // g  -> Sst (bf16, exact fit)
  float* T  = (float*)alloc((size_t)MM * HD * 4);   // qc -> gate
  float* beta = (float*)alloc((size_t)MM * HH * 4);
  float* fa = (float*)alloc((size_t)MM * DD * 4);   // -> dlast
  float* ga = (float*)alloc((size_t)MM * DD * 4);
  u16* fab = (u16*)alloc((size_t)MM * DD * 2);
  u16* gab = (u16*)alloc((size_t)MM * DD * 2);
  u16* Xp  = (u16*)alloc((size_t)NU * 8192 * 2);    // X~ transposed dense
  u16* Qp  = WkT;                                   // alias WkT+WvT (16.78 MB)
  u16* Sst = (u16*)X3;
  u16* Mg  = (u16*)d_out;                           // 8 MB, dead until out_pass
  u16* Wg  = (u16*)d_out + (size_t)NU * 4096;       // 16 MB

  dim3 tb(32, 8);
  const int n_full = MM * HD;

  // 1. convert + transpose weights
  cvt_bf16_kernel<<<(n_full + 255) / 256, 256, 0, stream>>>(hid, hidb, n_full);
  transpose_bf16_kernel<<<dim3(HD / 32, HID_ / 32), tb, 0, stream>>>(Wq, WqT, HID_, HD);
  transpose_bf16_kernel<<<dim3(HD / 32, HID_ / 32), tb, 0, stream>>>(Wk, WkT, HID_, HD);
  transpose_bf16_kernel<<<dim3(HD / 32, HID_ / 32), tb, 0, stream>>>(Wv, WvT, HID_, HD);
  transpose_bf16_kernel<<<dim3(HID_ / 32, HD / 32), tb, 0, stream>>>(Wo, WoT, HD, HID_);
  transpose_bf16_kernel<<<dim3(DD / 32, HID_ / 32), tb, 0, stream>>>(Wfa, WfaT, HID_, DD);
  transpose_bf16_kernel<<<dim3(DD / 32, HID_ / 32), tb, 0, stream>>>(Wga, WgaT, HID_, DD);
  transpose_bf16_kernel<<<dim3(HD / 32, DD / 32), tb, 0, stream>>>(Wfb, WfbT, DD, HD);
  transpose_bf16_kernel<<<dim3(HD / 32, DD / 32), tb, 0, stream>>>(Wgb, WgbT, DD, HD);

  // 2. projections
  gemm_bf16_kernel<<<dim3(HD / 128, MM / 128), 256, 0, stream>>>(hidb, WqT, X1, MM, HD, HID_);
  gemm_bf16_kernel<<<dim3(HD / 128, MM / 128), 256, 0, stream>>>(hidb, WkT, X2, MM, HD, HID_);
  gemm_bf16_kernel<<<dim3(HD / 128, MM / 128), 256, 0, stream>>>(hidb, WvT, X3, MM, HD, HID_);
  gemm_bf16_kernel<<<dim3(DD / 128, MM / 128), 256, 0, stream>>>(hidb, WfaT, fa, MM, DD, HID_);
  gemm_bf16_kernel<<<dim3(DD / 128, MM / 128), 256, 0, stream>>>(hidb, WgaT, ga, MM, DD, HID_);
  beta_kernel<<<MM, 256, 0, stream>>>(hid, Wb, beta);

  // 3. l2norm q,k
  l2norm_kernel<<<MM * HH / 4, 256, 0, stream>>>(X1);
  l2norm_kernel<<<MM * HH / 4, 256, 0, stream>>>(X2);

  // 4. conv+silu: qc=T<-X1, kc=X1<-X2, vc=X2<-X3 (X3 free)
  conv_silu_kernel<<<(n_full + 255) / 256, 256, 0, stream>>>(X1, conv_q, T, n_full);
  conv_silu_kernel<<<(n_full + 255) / 256, 256, 0, stream>>>(X2, conv_k, X1, n_full);
  conv_silu_kernel<<<(n_full + 255) / 256, 256, 0, stream>>>(X3, conv_v, X2, n_full);

  // 5. forget gate: glin = fa@Wfb -> X3, KDA transform in place
  cvt_bf16_kernel<<<(MM * DD + 255) / 256, 256, 0, stream>>>(fa, fab, MM * DD);
  gemm_bf16_kernel<<<dim3(HD / 128, MM / 128), 256, 0, stream>>>(fab, WfbT, X3, MM, HD, DD);
  kda_g_kernel<<<(n_full + 255) / 256, 256, 0, stream>>>(X3, A_log, dt_bias, n_full);

  // 6. chunked delta rule: prepA (MFMA A/G) -> solve -> state chain -> outputs
  chunk_prepA<<<NU, 256, 0, stream>>>(T, X1, X3, beta, WqT, Mg, Wg, fa, Qp, Xp);
  solve_kernel<<<NU, 256, 0, stream>>>(Mg, Wg, X2, beta, hidb);
  state_pass<<<dim3(8, 32), 256, 0, stream>>>(hidb, Xp, X2, fa, Sst);
  out_pass<<<NU, 256, 0, stream>>>(hidb, Qp, WqT, Sst, X2, out);

  // 7. output gate: gate = ga@Wgb -> T
  cvt_bf16_kernel<<<(MM * DD + 255) / 256, 256, 0, stream>>>(ga, gab, MM * DD);
  gemm_bf16_kernel<<<dim3(HD / 128, MM / 128), 256, 0, stream>>>(gab, WgbT, T, MM, HD, DD);

  // 8. RMSNorm + sigmoid gate -> bf16 preout
  gate_rms_kernel<<<MM * HH / 4, 256, 0, stream>>>(out, T, rms_scale, hidb);

  // 9. final projection
  gemm_bf16_kernel<<<dim3(HID_ / 128, MM / 128), 256, 0, stream>>>(hidb, WoT, out, MM, HID_, HD);
}

// Round 5
// 1093.547 us; speedup vs baseline: 1.1677x; 1.1677x over previous
//
#include <hip/hip_runtime.h>
#include <cstdint>

// Problem constants: B=2, S=2048, HID=2048, H=16, D=128, K=4
#define BB 2
#define SS 2048
#define HID_ 2048
#define HH 16
#define DD 128
#define HD 2048
#define MM 4096
#define CC 64        // chunk length
#define NCH 32       // chunks per sequence
#define NU 1024      // units = 32 (b*h) * 32 chunks

typedef unsigned short u16;
typedef __bf16 bf16x8 __attribute__((ext_vector_type(8)));
typedef float f32x4 __attribute__((ext_vector_type(4)));
typedef unsigned short u16x8 __attribute__((ext_vector_type(8)));

__device__ __forceinline__ u16 f2bf(float f) {
  unsigned u = __float_as_uint(f);
  u += 0x7FFFu + ((u >> 16) & 1u);   // RNE
  return (u16)(u >> 16);
}
__device__ __forceinline__ float blo(unsigned u) { return __uint_as_float(u << 16); }
__device__ __forceinline__ float bhi(unsigned u) { return __uint_as_float(u & 0xffff0000u); }
__device__ __forceinline__ float sigmoidf_(float x) { return 1.0f / (1.0f + __expf(-x)); }

__device__ __forceinline__ void gll16(const void* g, void* l) {
  __builtin_amdgcn_global_load_lds((const __attribute__((address_space(1))) void*)g,
                                   (__attribute__((address_space(3))) void*)l, 16, 0, 0);
}

typedef union { unsigned q[4]; bf16x8 b; } fragu;

// build bf16x8 fragment  k[off..off+7] * exp(g - a)  (elementwise)
__device__ __forceinline__ bf16x8 decay_row8(const u16* kr, const float* gr, const float* ar, int off) {
  uint4 k8 = *(const uint4*)(kr + off);
  f32x4 g0 = *(const f32x4*)(gr + off);
  f32x4 g1 = *(const f32x4*)(gr + off + 4);
  f32x4 a0 = *(const f32x4*)(ar + off);
  f32x4 a1 = *(const f32x4*)(ar + off + 4);
  fragu r;
  r.q[0] = (unsigned)f2bf(blo(k8.x) * __expf(g0[0] - a0[0])) |
           ((unsigned)f2bf(bhi(k8.x) * __expf(g0[1] - a0[1])) << 16);
  r.q[1] = (unsigned)f2bf(blo(k8.y) * __expf(g0[2] - a0[2])) |
           ((unsigned)f2bf(bhi(k8.y) * __expf(g0[3] - a0[3])) << 16);
  r.q[2] = (unsigned)f2bf(blo(k8.z) * __expf(g1[0] - a1[0])) |
           ((unsigned)f2bf(bhi(k8.z) * __expf(g1[1] - a1[1])) << 16);
  r.q[3] = (unsigned)f2bf(blo(k8.w) * __expf(g1[2] - a1[2])) |
           ((unsigned)f2bf(bhi(k8.w) * __expf(g1[3] - a1[3])) << 16);
  return r.b;
}

// ---------------- elementwise f32 -> bf16 ----------------
__global__ void cvt_bf16_kernel(const float* __restrict__ in, u16* __restrict__ out, int n) {
  int i = blockIdx.x * blockDim.x + threadIdx.x;
  if (i < n) out[i] = f2bf(in[i]);
}

// ---------------- transpose + convert: in[K][N] f32 -> out[N][K] bf16 ----------------
__global__ __launch_bounds__(256) void transpose_bf16_kernel(
    const float* __restrict__ in, u16* __restrict__ out, int K, int N) {
  __shared__ float tile[32][33];
  int n0 = blockIdx.x * 32, k0 = blockIdx.y * 32;
  int tx = threadIdx.x, ty = threadIdx.y;
#pragma unroll
  for (int i = 0; i < 32; i += 8)
    tile[ty + i][tx] = in[(size_t)(k0 + ty + i) * N + (n0 + tx)];
  __syncthreads();
#pragma unroll
  for (int i = 0; i < 32; i += 8)
    out[(size_t)(n0 + ty + i) * K + (k0 + tx)] = f2bf(tile[tx][ty + i]);
}

// ---------------- bf16 MFMA GEMM: C[M][N] f32 = A[M][K] @ Bt[N][K]^T ----------------
__global__ __launch_bounds__(256) void gemm_bf16_kernel(
    const u16* __restrict__ A, const u16* __restrict__ Bt, float* __restrict__ C,
    int M, int N, int K) {
  __shared__ u16 As[128 * 32];
  __shared__ u16 Bs[128 * 32];
  const int tid = threadIdx.x;
  const int tileN = blockIdx.x * 128, tileM = blockIdx.y * 128;
  const int lane = tid & 63, wv = tid >> 6;
  const int wm = (wv & 1) * 64, wn = (wv >> 1) * 64;
  const int frm = lane & 15, fk = (lane >> 4) * 8;
  const int srow0 = 32 * wv + (lane >> 2);
  const int scol8 = (lane & 3) * 8;
  const u16* Ab0 = A + (size_t)(tileM + srow0) * K + scol8;
  const u16* Ab1 = A + (size_t)(tileM + srow0 + 16) * K + scol8;
  const u16* Bb0 = Bt + (size_t)(tileN + srow0) * K + scol8;
  const u16* Bb1 = Bt + (size_t)(tileN + srow0 + 16) * K + scol8;
  u16* AsL0 = &As[1024 * wv];
  u16* AsL1 = &As[1024 * wv + 512];
  u16* BsL0 = &Bs[1024 * wv];
  u16* BsL1 = &Bs[1024 * wv + 512];
  f32x4 acc[4][4];
#pragma unroll
  for (int i = 0; i < 4; ++i)
#pragma unroll
    for (int j = 0; j < 4; ++j) acc[i][j] = (f32x4)0.0f;
  for (int k0 = 0; k0 < K; k0 += 32) {
    gll16(Ab0 + k0, AsL0);
    gll16(Ab1 + k0, AsL1);
    gll16(Bb0 + k0, BsL0);
    gll16(Bb1 + k0, BsL1);
    __syncthreads();
    bf16x8 af[4], bfr[4];
#pragma unroll
    for (int t = 0; t < 4; ++t)
      af[t] = *(const bf16x8*)(&As[(wm + t * 16 + frm) * 32 + fk]);
#pragma unroll
    for (int t = 0; t < 4; ++t)
      bfr[t] = *(const bf16x8*)(&Bs[(wn + t * 16 + frm) * 32 + fk]);
#pragma unroll
    for (int mt = 0; mt < 4; ++mt)
#pragma unroll
      for (int nt = 0; nt < 4; ++nt)
        acc[mt][nt] = __builtin_amdgcn_mfma_f32_16x16x32_bf16(af[mt], bfr[nt], acc[mt][nt], 0, 0, 0);
    __syncthreads();
  }
  const int crow = (lane >> 4) * 4, ccol = lane & 15;
#pragma unroll
  for (int mt = 0; mt < 4; ++mt)
#pragma unroll
    for (int nt = 0; nt < 4; ++nt) {
      float* cp = C + (size_t)(tileM + wm + mt * 16 + crow) * N + (tileN + wn + nt * 16 + ccol);
#pragma unroll
      for (int i = 0; i < 4; ++i) cp[(size_t)i * N] = acc[mt][nt][i];
    }
}

// ---------------- fused l2norm + causal dwconv(K=4) + SiLU; one wave/(token,head) ----------
__global__ __launch_bounds__(256) void l2conv_silu_kernel(
    const float* __restrict__ x, const float* __restrict__ w, float* __restrict__ y) {
  int idx = blockIdx.x * 4 + (threadIdx.x >> 6);   // (b*SS+s)*HH + h
  int lane = threadIdx.x & 63;
  int h = idx & (HH - 1);
  int s = (idx >> 4) & (SS - 1);
  const float* xp = x + (size_t)idx * DD + lane * 2;
  const float* wp = w + h * DD + lane * 2;
  float acc0 = 0.f, acc1 = 0.f;
#pragma unroll
  for (int t = 0; t < 4; ++t) {
    int d = t - 3;
    if (s + d >= 0) {
      float2 vv = *(const float2*)(xp + (ptrdiff_t)d * HD);
      float ss = vv.x * vv.x + vv.y * vv.y;
#pragma unroll
      for (int o = 32; o > 0; o >>= 1) ss += __shfl_xor(ss, o);
      float r = rsqrtf(ss + 1e-6f);
      float2 ww = *(const float2*)(wp + (size_t)t * HD);
      acc0 += ww.x * vv.x * r;
      acc1 += ww.y * vv.y * r;
    }
  }
  float2 o2;
  o2.x = acc0 * sigmoidf_(acc0);
  o2.y = acc1 * sigmoidf_(acc1);
  *(float2*)(y + (size_t)idx * DD + lane * 2) = o2;
}

// ---------------- causal depthwise conv (K=4) + SiLU (no norm; for v) ----------------
__global__ void conv_silu_kernel(const float* __restrict__ x, const float* __restrict__ w,
                                 float* __restrict__ y, int n) {
  int id = blockIdx.x * blockDim.x + threadIdx.x;
  if (id >= n) return;
  int c = id & (HD - 1);
  int s = (id >> 11) & (SS - 1);
  float acc = 0.f;
#pragma unroll
  for (int t = 0; t < 4; ++t) {
    int sp = s - 3 + t;
    if (sp >= 0) acc += w[t * HD + c] * x[id + (t - 3) * HD];
  }
  y[id] = acc * sigmoidf_(acc);
}

// ---------------- beta = sigmoid(hidden @ Wb) ----------------
__global__ __launch_bounds__(256) void beta_kernel(const float* __restrict__ hid,
                                                   const float* __restrict__ Wb,
                                                   float* __restrict__ beta) {
  int row = blockIdx.x;
  int tid = threadIdx.x;
  int h = tid & 15, chunk = tid >> 4;
  const float* hp = hid + (size_t)row * HID_;
  float acc = 0.f;
  int d0 = chunk * 128;
  for (int i = 0; i < 128; ++i) acc += hp[d0 + i] * Wb[(size_t)(d0 + i) * 16 + h];
  __shared__ float red[256];
  red[tid] = acc;
  __syncthreads();
  if (tid < 16) {
    float s = 0.f;
#pragma unroll
    for (int j = 0; j < 16; ++j) s += red[j * 16 + tid];
    beta[(size_t)row * 16 + tid] = 1.f / (1.f + __expf(-s));
  }
}

// ---------------- g = -exp(A_log[h]) * softplus(glin + dt_bias), in-place ----------------
__global__ void kda_g_kernel(float* __restrict__ glin, const float* __restrict__ A_log,
                             const float* __restrict__ dt_bias, int n) {
  int id = blockIdx.x * blockDim.x + threadIdx.x;
  if (id >= n) return;
  int c = id & (HD - 1);
  int h = c >> 7;
  float x = glin[id] + dt_bias[c];
  float sp = (x > 20.f) ? x : log1pf(__expf(x));
  glin[id] = -__expf(A_log[h]) * sp;
}

// ---------------- chunk_prepA: anchored-MFMA A/G + packed tensors ----------------
__global__ __launch_bounds__(256) void chunk_prepA(
    const float* __restrict__ q, const float* __restrict__ k,
    const float* __restrict__ g, const float* __restrict__ beta,
    u16* __restrict__ Gt, u16* __restrict__ Mg, u16* __restrict__ Wg,
    float* __restrict__ dl, u16* __restrict__ Qp, u16* __restrict__ Xp) {
  __shared__ float gcl[CC * 132];   // col 128 holds beta[t]
  __shared__ u16 kb[CC * 136];
  __shared__ u16 qd[16 * 128];
  __shared__ u16 Gli[16 * 64];
  __shared__ u16 MlI[16 * 64];
  const int tid = threadIdx.x;
  const int chunk = blockIdx.x & 31, bh = blockIdx.x >> 5;
  const int h = bh & 15, b = bh >> 4;
  const size_t unit = (size_t)bh * NCH + chunk;
  const size_t base = ((size_t)b * SS + (size_t)chunk * CC) * HD + (size_t)h * DD;
  const float scale = 0.08838834764831845f;
  const int w = tid >> 6, lane = tid & 63;
  const int frm = lane & 15, fk = (lane >> 4) * 8;
  const int crow = (lane >> 4) * 4, ccol = lane & 15;

  // phase 1: stage k (bf16), beta, cumsum g
  {
    int t = tid >> 2, seg = tid & 3;
    const float* kr = k + base + (size_t)t * HD + seg * 32;
    float kv[32];
#pragma unroll
    for (int i = 0; i < 8; ++i) *(f32x4*)&kv[4 * i] = *(const f32x4*)(kr + 4 * i);
    unsigned pu[16];
#pragma unroll
    for (int i = 0; i < 16; ++i)
      pu[i] = (unsigned)f2bf(kv[2 * i]) | ((unsigned)f2bf(kv[2 * i + 1]) << 16);
    uint4* dst = (uint4*)&kb[t * 136 + seg * 32];
#pragma unroll
    for (int i = 0; i < 4; ++i) dst[i] = make_uint4(pu[4 * i], pu[4 * i + 1], pu[4 * i + 2], pu[4 * i + 3]);
  }
  if (tid < CC) gcl[tid * 132 + 128] = beta[((size_t)b * SS + (size_t)chunk * CC + tid) * HH + h];
  if (tid < DD) {
    float acc = 0.f;
    for (int t = 0; t < CC; ++t) {
      acc += g[base + (size_t)t * HD + tid];
      gcl[t * 132 + tid] = acc;
    }
  }
  __syncthreads();

  // phase 2: I-blocks
#pragma unroll 1
  for (int I = 0; I < 4; ++I) {
    const int aI = 16 * I;
    for (int e = tid; e < 512; e += 256) ((unsigned*)Gli)[e] = 0;
    {
      int tl = tid >> 4, c0 = (tid & 15) * 8;
      const float* qr = q + base + (size_t)(aI + tl) * HD + c0;
      f32x4 q0 = *(const f32x4*)qr;
      f32x4 q1 = *(const f32x4*)(qr + 4);
      uint4 o;
      o.x = (unsigned)f2bf(q0[0] * scale) | ((unsigned)f2bf(q0[1] * scale) << 16);
      o.y = (unsigned)f2bf(q0[2] * scale) | ((unsigned)f2bf(q0[3] * scale) << 16);
      o.z = (unsigned)f2bf(q1[0] * scale) | ((unsigned)f2bf(q1[1] * scale) << 16);
      o.w = (unsigned)f2bf(q1[2] * scale) | ((unsigned)f2bf(q1[3] * scale) << 16);
      *(uint4*)&qd[tl * 128 + c0] = o;
    }
    __syncthreads();
    // diagonal 16x16 triangle
    {
      const int tl = tid >> 4, jl = tid & 15;
      const int rt = aI + tl, rj = aI + jl;
      float accA = 0.f, accG = 0.f;
#pragma unroll
      for (int c0 = 0; c0 < 128; c0 += 8) {
        f32x4 gt0 = *(const f32x4*)&gcl[rt * 132 + c0];
        f32x4 gt1 = *(const f32x4*)&gcl[rt * 132 + c0 + 4];
        f32x4 gj0 = *(const f32x4*)&gcl[rj * 132 + c0];
        f32x4 gj1 = *(const f32x4*)&gcl[rj * 132 + c0 + 4];
        uint4 kt4 = *(const uint4*)&kb[rt * 136 + c0];
        uint4 kj4 = *(const uint4*)&kb[rj * 136 + c0];
        uint4 qt4 = *(const uint4*)&qd[tl * 128 + c0];
        float e, p;
        e = __expf(gt0[0] - gj0[0]); p = blo(kj4.x) * e; accA += blo(kt4.x) * p; accG += blo(qt4.x) * p;
        e = __expf(gt0[1] - gj0[1]); p = bhi(kj4.x) * e; accA += bhi(kt4.x) * p; accG += bhi(qt4.x) * p;
        e = __expf(gt0[2] - gj0[2]); p = blo(kj4.y) * e; accA += blo(kt4.y) * p; accG += blo(qt4.y) * p;
        e = __expf(gt0[3] - gj0[3]); p = bhi(kj4.y) * e; accA += bhi(kt4.y) * p; accG += bhi(qt4.y) * p;
        e = __expf(gt1[0] - gj1[0]); p = blo(kj4.z) * e; accA += blo(kt4.z) * p; accG += blo(qt4.z) * p;
        e = __expf(gt1[1] - gj1[1]); p = bhi(kj4.z) * e; accA += bhi(kt4.z) * p; accG += bhi(qt4.z) * p;
        e = __expf(gt1[2] - gj1[2]); p = blo(kj4.w) * e; accA += blo(kt4.w) * p; accG += blo(qt4.w) * p;
        e = __expf(gt1[3] - gj1[3]); p = bhi(kj4.w) * e; accA += bhi(kt4.w) * p; accG += bhi(qt4.w) * p;
      }
      if (jl <= tl) Gli[tl * 64 + aI + jl] = f2bf(accG);
      if (jl < tl) MlI[tl * 64 + aI + jl] = f2bf(gcl[rt * 132 + 128] * accA);
    }
    // off-diagonal tiles via MFMA (wave 0: A, wave 1: G)
    if (w < 2) {
      const int rt = aI + frm;
      bf16x8 af[4];
#pragma unroll
      for (int kb2 = 0; kb2 < 4; ++kb2) {
        int off = kb2 * 32 + fk;
        if (w == 0)
          af[kb2] = decay_row8(&kb[rt * 136], &gcl[rt * 132], &gcl[aI * 132], off);
        else
          af[kb2] = decay_row8(&qd[frm * 128], &gcl[rt * 132], &gcl[aI * 132], off);
      }
      for (int J = 0; J < I; ++J) {
        const int rj = 16 * J + frm;
        f32x4 acc = (f32x4)0.f;
#pragma unroll
        for (int kb2 = 0; kb2 < 4; ++kb2) {
          int off = kb2 * 32 + fk;
          bf16x8 bf = decay_row8(&kb[rj * 136], &gcl[aI * 132], &gcl[rj * 132], off);
          acc = __builtin_amdgcn_mfma_f32_16x16x32_bf16(af[kb2], bf, acc, 0, 0, 0);
        }
        if (w == 0) {
#pragma unroll
          for (int i = 0; i < 4; ++i) {
            float bt = gcl[(aI + crow + i) * 132 + 128];
            MlI[(crow + i) * 64 + 16 * J + ccol] = f2bf(bt * acc[i]);
          }
        } else {
#pragma unroll
          for (int i = 0; i < 4; ++i)
            Gli[(crow + i) * 64 + 16 * J + ccol] = f2bf(acc[i]);
        }
      }
    }
    __syncthreads();
    // flush G, M, Q~ of this block
    if (tid < 128) {
      int t = tid >> 3, j0 = (tid & 7) * 8;
      *(uint4*)(Gt + unit * 4096 + (size_t)(aI + t) * 64 + j0) = *(const uint4*)&Gli[t * 64 + j0];
    } else {
      int t2 = (tid - 128) >> 3, j0 = ((tid - 128) & 7) * 8;
      *(uint4*)(Mg + unit * 4096 + (size_t)(aI + t2) * 64 + j0) = *(const uint4*)&MlI[t2 * 64 + j0];
    }
    {
      int tl = tid >> 4, c0 = (tid & 15) * 8;
      const int rt = aI + tl;
      uint4 q8 = *(const uint4*)&qd[tl * 128 + c0];
      f32x4 g0 = *(const f32x4*)&gcl[rt * 132 + c0];
      f32x4 g1 = *(const f32x4*)&gcl[rt * 132 + c0 + 4];
      uint4 o;
      o.x = (unsigned)f2bf(blo(q8.x) * __expf(g0[0])) | ((unsigned)f2bf(bhi(q8.x) * __expf(g0[1])) << 16);
      o.y = (unsigned)f2bf(blo(q8.y) * __expf(g0[2])) | ((unsigned)f2bf(bhi(q8.y) * __expf(g0[3])) << 16);
      o.z = (unsigned)f2bf(blo(q8.z) * __expf(g1[0])) | ((unsigned)f2bf(bhi(q8.z) * __expf(g1[1])) << 16);
      o.w = (unsigned)f2bf(blo(q8.w) * __expf(g1[2])) | ((unsigned)f2bf(bhi(q8.w) * __expf(g1[3])) << 16);
      *(uint4*)(Qp + unit * 8192 + (size_t)rt * 128 + c0) = o;
    }
    __syncthreads();
  }

  // phase 3: X~ transposed [k][t]
#pragma unroll
  for (int r = 0; r < 4; ++r) {
    int c = (tid >> 3) + r * 32;
    int t8 = (tid & 7) * 8;
    float gl = gcl[63 * 132 + c];
    unsigned pu[4];
#pragma unroll
    for (int i = 0; i < 4; ++i) {
      int t0 = t8 + 2 * i;
      float x0 = blo((unsigned)kb[t0 * 136 + c]) * __expf(gl - gcl[t0 * 132 + c]);
      float x1 = blo((unsigned)kb[(t0 + 1) * 136 + c]) * __expf(gl - gcl[(t0 + 1) * 132 + c]);
      pu[i] = (unsigned)f2bf(x0) | ((unsigned)f2bf(x1) << 16);
    }
    *(uint4*)(Xp + unit * 8192 + (size_t)c * 64 + t8) = make_uint4(pu[0], pu[1], pu[2], pu[3]);
  }
  if (tid < DD) dl[unit * DD + tid] = __expf(gcl[63 * 132 + tid]);
  // phase 4: W = beta * k * e^gc
  {
    int t = tid >> 2, c0 = (tid & 3) * 32;
    float bt = gcl[t * 132 + 128];
#pragma unroll
    for (int s4 = 0; s4 < 4; ++s4) {
      uint4 k8 = *(const uint4*)&kb[t * 136 + c0 + s4 * 8];
      f32x4 g0 = *(const f32x4*)&gcl[t * 132 + c0 + s4 * 8];
      f32x4 g1 = *(const f32x4*)&gcl[t * 132 + c0 + s4 * 8 + 4];
      uint4 o;
      o.x = (unsigned)f2bf(bt * blo(k8.x) * __expf(g0[0])) | ((unsigned)f2bf(bt * bhi(k8.x) * __expf(g0[1])) << 16);
      o.y = (unsigned)f2bf(bt * blo(k8.y) * __expf(g0[2])) | ((unsigned)f2bf(bt * bhi(k8.y) * __expf(g0[3])) << 16);
      o.z = (unsigned)f2bf(bt * blo(k8.z) * __expf(g1[0])) | ((unsigned)f2bf(bt * bhi(k8.z) * __expf(g1[1])) << 16);
      o.w = (unsigned)f2bf(bt * blo(k8.w) * __expf(g1[2])) | ((unsigned)f2bf(bt * bhi(k8.w) * __expf(g1[3])) << 16);
      *(uint4*)(Wg + unit * 8192 + (size_t)t * 128 + c0 + s4 * 8) = o;
    }
  }
}

// ---- forced-unroll forward substitution (compile-time indices -> registers) ----
template<int I>
__device__ __forceinline__ void solve_step(float (&X)[CC], const u16* Ml) {
  float acc = X[I];
#pragma unroll
  for (int jb = 0; jb * 8 < I; ++jb) {
    uint4 mm = *(const uint4*)&Ml[I * CC + jb * 8];
    if (jb * 8 + 0 < I) acc -= blo(mm.x) * X[jb * 8 + 0];
    if (jb * 8 + 1 < I) acc -= bhi(mm.x) * X[jb * 8 + 1];
    if (jb * 8 + 2 < I) acc -= blo(mm.y) * X[jb * 8 + 2];
    if (jb * 8 + 3 < I) acc -= bhi(mm.y) * X[jb * 8 + 3];
    if (jb * 8 + 4 < I) acc -= blo(mm.z) * X[jb * 8 + 4];
    if (jb * 8 + 5 < I) acc -= bhi(mm.z) * X[jb * 8 + 5];
    if (jb * 8 + 6 < I) acc -= blo(mm.w) * X[jb * 8 + 6];
    if (jb * 8 + 7 < I) acc -= bhi(mm.w) * X[jb * 8 + 7];
  }
  X[I] = acc;
}
template<int I>
__device__ __forceinline__ void solve_rec(float (&X)[CC], const u16* Ml) {
  if constexpr (I < CC) {
    solve_step<I>(X, Ml);
    solve_rec<I + 1>(X, Ml);
  }
}

// ---------------- solve_kernel: (I+M) X = [beta*V | W]; P, Uv out ----------------
__global__ __launch_bounds__(256) void solve_kernel(
    const u16* __restrict__ Mg, const u16* __restrict__ Wg,
    float* __restrict__ v, const float* __restrict__ beta, u16* __restrict__ P) {
  __shared__ u16 Ml[CC * CC];
  __shared__ float betal[CC];
  const int tid = threadIdx.x;
  const int chunk = blockIdx.x & 31, bh = blockIdx.x >> 5;
  const int h = bh & 15, b = bh >> 4;
  const size_t unit = (size_t)bh * NCH + chunk;
  const size_t base = ((size_t)b * SS + (size_t)chunk * CC) * HD + (size_t)h * DD;
  ((uint4*)Ml)[tid] = ((const uint4*)(Mg + unit * 4096))[tid];
  ((uint4*)Ml)[tid + 256] = ((const uint4*)(Mg + unit * 4096))[tid + 256];
  if (tid < CC) betal[tid] = beta[((size_t)b * SS + (size_t)chunk * CC + tid) * HH + h];
  __syncthreads();
  const int c = tid & 127;
  const bool isV = tid < 128;
  float X[CC];
#pragma unroll
  for (int t = 0; t < CC; ++t) {
    if (isV) X[t] = betal[t] * v[base + (size_t)t * HD + c];
    else X[t] = blo((unsigned)Wg[unit * 8192 + t * 128 + c]);
  }
  solve_rec<1>(X, Ml);
#pragma unroll
  for (int t = 0; t < CC; ++t) {
    if (isV) v[base + (size_t)t * HD + c] = X[t];
    else P[unit * 8192 + t * 128 + c] = f2bf(X[t]);
  }
}

// ---------------- state_pass: sequential S-chain; grid (8 vslices, 32 bh) ----------------
__global__ __launch_bounds__(256) void state_pass(
    const u16* __restrict__ P, const u16* __restrict__ Xp,
    const float* __restrict__ Uvg, const float* __restrict__ dl,
    u16* __restrict__ Sst) {
  __shared__ u16 Pb[64 * 136];    // [t][k] padded
  __shared__ u16 Xb[128 * 72];    // [k][t] padded
  __shared__ float S[128 * 20];   // [k][c] c<16, padded
  __shared__ float U[64 * 20];    // [t][c]
  __shared__ float dll[128];
  const int tid = threadIdx.x;
  const int vs = blockIdx.x, bh = blockIdx.y;
  const int h = bh & 15, b = bh >> 4;
  for (int i = tid; i < 128 * 20; i += 256) S[i] = 0.f;
  __syncthreads();
  for (int c = 0; c < NCH; ++c) {
    const size_t unit = (size_t)bh * NCH + c;
    const size_t base = ((size_t)b * SS + (size_t)c * CC) * HD + (size_t)h * DD + vs * 16;
#pragma unroll
    for (int r = 0; r < 4; ++r) {
      int e = r * 256 + tid;
      int t = e >> 4, kp = (e & 15) * 8;
      *(uint4*)&Pb[t * 136 + kp] = ((const uint4*)(P + unit * 8192))[e];
      int kk = e >> 3, tp = (e & 7) * 8;
      *(uint4*)&Xb[kk * 72 + tp] = ((const uint4*)(Xp + unit * 8192))[e];
    }
    {
      int t = tid >> 2, cg = tid & 3;
      *(f32x4*)&U[t * 20 + cg * 4] = *(const f32x4*)(Uvg + base + (size_t)t * HD + cg * 4);
    }
    if (tid < 128) dll[tid] = dl[unit * DD + tid];
    {
      int v2 = tid >> 4, kq = tid & 15;
      unsigned pu[4];
#pragma unroll
      for (int j = 0; j < 4; ++j) {
        float a = S[(kq * 8 + 2 * j) * 20 + v2];
        float bb = S[(kq * 8 + 2 * j + 1) * 20 + v2];
        pu[j] = (unsigned)f2bf(a) | ((unsigned)f2bf(bb) << 16);
      }
      *(uint4*)(Sst + unit * 16384 + (size_t)(vs * 16 + v2) * 128 + kq * 8) =
          make_uint4(pu[0], pu[1], pu[2], pu[3]);
    }
    __syncthreads();
    {
      const int t = tid >> 2, cg = tid & 3;
      f32x4 u = *(f32x4*)&U[t * 20 + cg * 4];
      f32x4 acc = (f32x4)0.f;
      for (int kk = 0; kk < 128; kk += 4) {
        uint2 pk = *(const uint2*)&Pb[t * 136 + kk];
        f32x4 s0 = *(const f32x4*)&S[(kk + 0) * 20 + cg * 4];
        f32x4 s1 = *(const f32x4*)&S[(kk + 1) * 20 + cg * 4];
        f32x4 s2 = *(const f32x4*)&S[(kk + 2) * 20 + cg * 4];
        f32x4 s3 = *(const f32x4*)&S[(kk + 3) * 20 + cg * 4];
        acc += blo(pk.x) * s0;
        acc += bhi(pk.x) * s1;
        acc += blo(pk.y) * s2;
        acc += bhi(pk.y) * s3;
      }
      u -= acc;
      *(f32x4*)&U[t * 20 + cg * 4] = u;
    }
    __syncthreads();
    {
      const int kk = tid >> 1, cg2 = tid & 1;
      f32x4 sa = *(f32x4*)&S[kk * 20 + cg2 * 8];
      f32x4 sb = *(f32x4*)&S[kk * 20 + cg2 * 8 + 4];
      float dk = dll[kk];
      sa *= dk; sb *= dk;
      for (int t4 = 0; t4 < 64; t4 += 4) {
        uint2 xv = *(const uint2*)&Xb[kk * 72 + t4];
        float x0 = blo(xv.x), x1 = bhi(xv.x), x2 = blo(xv.y), x3 = bhi(xv.y);
        f32x4 u0a = *(const f32x4*)&U[(t4 + 0) * 20 + cg2 * 8];
        f32x4 u0b = *(const f32x4*)&U[(t4 + 0) * 20 + cg2 * 8 + 4];
        f32x4 u1a = *(const f32x4*)&U[(t4 + 1) * 20 + cg2 * 8];
        f32x4 u1b = *(const f32x4*)&U[(t4 + 1) * 20 + cg2 * 8 + 4];
        f32x4 u2a = *(const f32x4*)&U[(t4 + 2) * 20 + cg2 * 8];
        f32x4 u2b = *(const f32x4*)&U[(t4 + 2) * 20 + cg2 * 8 + 4];
        f32x4 u3a = *(const f32x4*)&U[(t4 + 3) * 20 + cg2 * 8];
        f32x4 u3b = *(const f32x4*)&U[(t4 + 3) * 20 + cg2 * 8 + 4];
        sa += x0 * u0a; sb += x0 * u0b;
        sa += x1 * u1a; sb += x1 * u1b;
        sa += x2 * u2a; sb += x2 * u2b;
        sa += x3 * u3a; sb += x3 * u3b;
      }
      *(f32x4*)&S[kk * 20 + cg2 * 8] = sa;
      *(f32x4*)&S[kk * 20 + cg2 * 8 + 4] = sb;
    }
    __syncthreads();
  }
}

// ---------------- out_pass: o = Q~*S + G*(Uv - P*S), MFMA; grid 1024 ----------------
__global__ __launch_bounds__(256) void out_pass(
    const u16* __restrict__ P, const u16* __restrict__ Qp,
    const u16* __restrict__ G, const u16* __restrict__ Sst,
    const float* __restrict__ Uvg, float* __restrict__ attn) {
  __shared__ u16 Sb[128 * 136];   // [v][k]
  __shared__ u16 Pb[64 * 136];    // [t][k]
  __shared__ u16 Qb[64 * 136];    // [t][k]
  __shared__ u16 Gb[64 * 72];     // [t][j]
  __shared__ u16 Ub[128 * 72];    // U^T [v][t]
  const int tid = threadIdx.x;
  const int unit = blockIdx.x;
  const int bh = unit >> 5, c = unit & 31;
  const int h = bh & 15, b = bh >> 4;
  const size_t base = ((size_t)b * SS + (size_t)c * CC) * HD + (size_t)h * DD;
#pragma unroll
  for (int r = 0; r < 8; ++r) {
    int e = r * 256 + tid;
    int v = e >> 4, kp = (e & 15) * 8;
    *(uint4*)&Sb[v * 136 + kp] = ((const uint4*)(Sst + (size_t)unit * 16384))[e];
  }
#pragma unroll
  for (int r = 0; r < 4; ++r) {
    int e = r * 256 + tid;
    int t = e >> 4, kp = (e & 15) * 8;
    *(uint4*)&Pb[t * 136 + kp] = ((const uint4*)(P + (size_t)unit * 8192))[e];
    *(uint4*)&Qb[t * 136 + kp] = ((const uint4*)(Qp + (size_t)unit * 8192))[e];
  }
#pragma unroll
  for (int r = 0; r < 2; ++r) {
    int e = r * 256 + tid;
    int t = e >> 3, jp = (e & 7) * 8;
    *(uint4*)&Gb[t * 72 + jp] = ((const uint4*)(G + (size_t)unit * 4096))[e];
  }
  __syncthreads();
  const int w = tid >> 6, lane = tid & 63;
  const int frm = lane & 15, fk = (lane >> 4) * 8;
  const int crow = (lane >> 4) * 4, ccol = lane & 15;
  bf16x8 Pf[4], Qf[4], Gf[2];
#pragma unroll
  for (int kb2 = 0; kb2 < 4; ++kb2) {
    Pf[kb2] = *(const bf16x8*)&Pb[(w * 16 + frm) * 136 + kb2 * 32 + fk];
    Qf[kb2] = *(const bf16x8*)&Qb[(w * 16 + frm) * 136 + kb2 * 32 + fk];
  }
#pragma unroll
  for (int kb2 = 0; kb2 < 2; ++kb2)
    Gf[kb2] = *(const bf16x8*)&Gb[(w * 16 + frm) * 72 + kb2 * 32 + fk];
  f32x4 aps[8], ao[8];
#pragma unroll
  for (int nt = 0; nt < 8; ++nt) { aps[nt] = (f32x4)0.f; ao[nt] = (f32x4)0.f; }
#pragma unroll
  for (int nt = 0; nt < 8; ++nt)
#pragma unroll
    for (int kb2 = 0; kb2 < 4; ++kb2) {
      bf16x8 sf = *(const bf16x8*)&Sb[(nt * 16 + frm) * 136 + kb2 * 32 + fk];
      aps[nt] = __builtin_amdgcn_mfma_f32_16x16x32_bf16(Pf[kb2], sf, aps[nt], 0, 0, 0);
      ao[nt] = __builtin_amdgcn_mfma_f32_16x16x32_bf16(Qf[kb2], sf, ao[nt], 0, 0, 0);
    }
#pragma unroll
  for (int nt = 0; nt < 8; ++nt) {
    float un[4];
#pragma unroll
    for (int i = 0; i < 4; ++i) {
      float uv = Uvg[base + (size_t)(w * 16 + crow + i) * HD + nt * 16 + ccol];
      un[i] = uv - aps[nt][i];
    }
    uint2 pk = make_uint2((unsigned)f2bf(un[0]) | ((unsigned)f2bf(un[1]) << 16),
                          (unsigned)f2bf(un[2]) | ((unsigned)f2bf(un[3]) << 16));
    *(uint2*)&Ub[(nt * 16 + ccol) * 72 + w * 16 + crow] = pk;
  }
  __syncthreads();
#pragma unroll
  for (int nt = 0; nt < 8; ++nt)
#pragma unroll
    for (int kb2 = 0; kb2 < 2; ++kb2) {
      bf16x8 uf = *(const bf16x8*)&Ub[(nt * 16 + frm) * 72 + kb2 * 32 + fk];
      ao[nt] = __builtin_amdgcn_mfma_f32_16x16x32_bf16(Gf[kb2], uf, ao[nt], 0, 0, 0);
    }
#pragma unroll
  for (int nt = 0; nt < 8; ++nt)
#pragma unroll
    for (int i = 0; i < 4; ++i)
      attn[base + (size_t)(w * 16 + crow + i) * HD + nt * 16 + ccol] = ao[nt][i];
}

// ---------------- RMSNorm * rms_scale * sigmoid(gate) -> bf16 preout ----------------
__global__ __launch_bounds__(256) void gate_rms_kernel(
    const float* __restrict__ attn, const float* __restrict__ gate,
    const float* __restrict__ rms_scale, u16* __restrict__ preout) {
  int idx = blockIdx.x * 4 + (threadIdx.x >> 6);
  int lane = threadIdx.x & 63;
  const float* ap = attn + (size_t)idx * DD;
  const float* gp = gate + (size_t)idx * DD;
  float2 a = *(const float2*)(ap + lane * 2);
  float ss = a.x * a.x + a.y * a.y;
#pragma unroll
  for (int o = 32; o > 0; o >>= 1) ss += __shfl_xor(ss, o);
  float r = rsqrtf(ss * (1.0f / 128.0f) + 1e-5f);
  float2 gg = *(const float2*)(gp + lane * 2);
  int d = lane * 2;
  float o0 = a.x * r * rms_scale[d] * sigmoidf_(gg.x);
  float o1 = a.y * r * rms_scale[d + 1] * sigmoidf_(gg.y);
  preout[(size_t)idx * DD + d] = f2bf(o0);
  preout[(size_t)idx * DD + d + 1] = f2bf(o1);
}

extern "C" void kernel_launch(void* const* d_in, const int* in_sizes, int n_in,
                              void* d_out, int out_size, void* d_ws, size_t ws_size,
                              hipStream_t stream) {
  const float* hid = (const float*)d_in[0];
  const float* Wq = (const float*)d_in[1];
  const float* Wk = (const float*)d_in[2];
  const float* Wv = (const float*)d_in[3];
  const float* conv_q = (const float*)d_in[4];
  const float* conv_k = (const float*)d_in[5];
  const float* conv_v = (const float*)d_in[6];
  const float* Wb = (const float*)d_in[7];
  const float* Wfa = (const float*)d_in[8];
  const float* Wfb = (const float*)d_in[9];
  const float* Wga = (const float*)d_in[10];
  const float* Wgb = (const float*)d_in[11];
  const float* A_log = (const float*)d_in[12];
  const float* dt_bias = (const float*)d_in[13];
  const float* rms_scale = (const float*)d_in[14];
  const float* Wo = (const float*)d_in[15];
  float* out = (float*)d_out;
  (void)in_sizes; (void)n_in; (void)out_size; (void)ws_size;

  char* w = (char*)d_ws;
  size_t off = 0;
  auto alloc = [&](size_t bytes) -> void* {
    void* p = w + off;
    off += (bytes + 255) & ~(size_t)255;
    return p;
  };
  u16* hidb = (u16*)alloc((size_t)MM * HID_ * 2);   // -> P (dense), then preout
  u16* WqT  = (u16*)alloc((size_t)HD * HID_ * 2);   // -> G (dense)
  u16* WkT  = (u16*)alloc((size_t)HD * HID_ * 2);   // -> Qp (with WvT, contiguous)
  u16* WvT  = (u16*)alloc((size_t)HD * HID_ * 2);
  u16* WoT  = (u16*)alloc((size_t)HID_ * HD * 2);
  u16* WfaT = (u16*)alloc((size_t)DD * HID_ * 2);
  u16* WgaT = (u16*)alloc((size_t)DD * HID_ * 2);
  u16* WfbT = (u16*)alloc((size_t)HD * DD * 2);
  u16* WgbT = (u16*)alloc((size_t)HD * DD * 2);
  float* X1 = (float*)alloc((size_t)MM * HD * 4);   // kproj -> kc
  float* X2 = (float*)alloc((size_t)MM * HD * 4);   // vproj -> vc -> Uv (in place)
  float* X3 = (float*)alloc((size_t)MM * HD * 4);   // g  -> Sst (bf16, exact fit)
  float* T  = (float*)alloc((size_t)MM * HD * 4);   // qc -> gate
  float* beta = (float*)alloc((size_t)MM * HH * 4);
  float* fa = (float*)alloc((size_t)MM * DD * 4);   // -> dlast
  float* ga = (float*)alloc((size_t)MM * DD * 4);
  u16* fab = (u16*)alloc((size_t)MM * DD * 2);
  u16* gab = (u16*)alloc((size_t)MM * DD * 2);
  u16* Xp  = (u16*)alloc((size_t)NU * 8192 * 2);    // X~ transposed dense
  u16* Qp  = WkT;                                   // alias WkT+WvT (16.78 MB)
  u16* Sst = (u16*)X3;
  u16* Mg  = (u16*)d_out;                           // 8 MB, dead until out_pass
  u16* Wg  = (u16*)d_out + (size_t)NU * 4096;       // 16 MB

  dim3 tb(32, 8);
  const int n_full = MM * HD;

  // 1. convert + transpose weights
  cvt_bf16_kernel<<<(n_full + 255) / 256, 256, 0, stream>>>(hid, hidb, n_full);
  transpose_bf16_kernel<<<dim3(HD / 32, HID_ / 32), tb, 0, stream>>>(Wq, WqT, HID_, HD);
  transpose_bf16_kernel<<<dim3(HD / 32, HID_ / 32), tb, 0, stream>>>(Wk, WkT, HID_, HD);
  transpose_bf16_kernel<<<dim3(HD / 32, HID_ / 32), tb, 0, stream>>>(Wv, WvT, HID_, HD);
  transpose_bf16_kernel<<<dim3(HID_ / 32, HD / 32), tb, 0, stream>>>(Wo, WoT, HD, HID_);
  transpose_bf16_kernel<<<dim3(DD / 32, HID_ / 32), tb, 0, stream>>>(Wfa, WfaT, HID_, DD);
  transpose_bf16_kernel<<<dim3(DD / 32, HID_ / 32), tb, 0, stream>>>(Wga, WgaT, HID_, DD);
  transpose_bf16_kernel<<<dim3(HD / 32, DD / 32), tb, 0, stream>>>(Wfb, WfbT, DD, HD);
  transpose_bf16_kernel<<<dim3(HD / 32, DD / 32), tb, 0, stream>>>(Wgb, WgbT, DD, HD);

  // 2. projections
  gemm_bf16_kernel<<<dim3(HD / 128, MM / 128), 256, 0, stream>>>(hidb, WqT, X1, MM, HD, HID_);
  gemm_bf16_kernel<<<dim3(HD / 128, MM / 128), 256, 0, stream>>>(hidb, WkT, X2, MM, HD, HID_);
  gemm_bf16_kernel<<<dim3(HD / 128, MM / 128), 256, 0, stream>>>(hidb, WvT, X3, MM, HD, HID_);
  gemm_bf16_kernel<<<dim3(DD / 128, MM / 128), 256, 0, stream>>>(hidb, WfaT, fa, MM, DD, HID_);
  gemm_bf16_kernel<<<dim3(DD / 128, MM / 128), 256, 0, stream>>>(hidb, WgaT, ga, MM, DD, HID_);
  beta_kernel<<<MM, 256, 0, stream>>>(hid, Wb, beta);

  // 3+4. fused l2norm+conv+silu for q,k; plain conv for v
  //      qc = T <- X1 ; kc = X1 <- X2 ; vc = X2 <- X3 (X3 then free)
  l2conv_silu_kernel<<<MM * HH / 4, 256, 0, stream>>>(X1, conv_q, T);
  l2conv_silu_kernel<<<MM * HH / 4, 256, 0, stream>>>(X2, conv_k, X1);
  conv_silu_kernel<<<(n_full + 255) / 256, 256, 0, stream>>>(X3, conv_v, X2, n_full);

  // 5. forget gate: glin = fa@Wfb -> X3, KDA transform in place
  cvt_bf16_kernel<<<(MM * DD + 255) / 256, 256, 0, stream>>>(fa, fab, MM * DD);
  gemm_bf16_kernel<<<dim3(HD / 128, MM / 128), 256, 0, stream>>>(fab, WfbT, X3, MM, HD, DD);
  kda_g_kernel<<<(n_full + 255) / 256, 256, 0, stream>>>(X3, A_log, dt_bias, n_full);

  // 6. chunked delta rule: prepA (MFMA A/G) -> solve -> state chain -> outputs
  chunk_prepA<<<NU, 256, 0, stream>>>(T, X1, X3, beta, WqT, Mg, Wg, fa, Qp, Xp);
  solve_kernel<<<NU, 256, 0, stream>>>(Mg, Wg, X2, beta, hidb);
  state_pass<<<dim3(8, 32), 256, 0, stream>>>(hidb, Xp, X2, fa, Sst);
  out_pass<<<NU, 256, 0, stream>>>(hidb, Qp, WqT, Sst, X2, out);

  // 7. output gate: gate = ga@Wgb -> T
  cvt_bf16_kernel<<<(MM * DD + 255) / 256, 256, 0, stream>>>(ga, gab, MM * DD);
  gemm_bf16_kernel<<<dim3(HD / 128, MM / 128), 256, 0, stream>>>(gab, WgbT, T, MM, HD, DD);

  // 8. RMSNorm + sigmoid gate -> bf16 preout
  gate_rms_kernel<<<MM * HH / 4, 256, 0, stream>>>(out, T, rms_scale, hidb);

  // 9. final projection
  gemm_bf16_kernel<<<dim3(HID_ / 128, MM / 128), 256, 0, stream>>>(hidb, WoT, out, MM, HID_, HD);
}